// Round 1
// 182.870 us; speedup vs baseline: 1.0179x; 1.0179x over previous
//
#include <hip/hip_runtime.h>
#include <hip/hip_bf16.h>

typedef __hip_bfloat16 bf16;
typedef __attribute__((ext_vector_type(8))) short bf16x8;
typedef __attribute__((ext_vector_type(4))) float f32x4;

#define N_NODE 20000
#define D      128
#define NEDGE  300000
#define NROW   (3 * N_NODE)          // CSR rows: [rev | ind | dd] x dst-node
#define NBIN   ((NROW + 255) >> 8)   // 235 bins of 256 rows
#define NB3    220                   // bin-hist / binscat blocks (220*4096 >= 900000)
#define CHUNK  4096
#define GBE    ((N_NODE + 63) / 64)  // gemm blocks per etype = 313
#define GEMMB  (3 * GBE)             // 939
#define WT_LD  132                   // padded LDS leading dim (bank-conflict-free)

__device__ __forceinline__ short f2bs(float x) {
    bf16 h = __float2bfloat16(x);
    short s; __builtin_memcpy(&s, &h, 2); return s;
}

// ================================================================ K_A
// Fused: blocks [0, GEMMB) do the 3 MFMA GEMMs + projections; blocks
// [GEMMB, GEMMB+NB3) histogram the edge bins (per-block partials, NO atomics,
// no zero-init needed) — fully overlapped, one launch.
// GEMM: block = 4 waves x 16 rows; W transposed+padded bf16 in LDS; 32x
// mfma_16x16x32_bf16/wave. Layouts (m89/m120): A[m=lane&15][k=quad*8+j];
// B[k=quad*8+j][n=lane&15]; D: row=quad*4+reg, col=lane&15. el/er cross-
// wiring: t=0 Wh_rev->el[rev],er[ind]; t=1 Wh_ind->el[ind],er[rev]; t=2 dd.
union SharedA {
    short Wt[D * WT_LD];   // 33,792 B (gemm branch)
    int   h[NBIN];         //    940 B (hist branch)
};

__global__ __launch_bounds__(256) void gemm_and_count(
    const float* __restrict__ feat_drug, const float* __restrict__ feat_dis,
    const float* __restrict__ W_ind, const float* __restrict__ b_ind,
    const float* __restrict__ a_ind,
    const float* __restrict__ W_rev, const float* __restrict__ b_rev,
    const float* __restrict__ a_rev,
    const float* __restrict__ W_dd, const float* __restrict__ b_dd,
    const float* __restrict__ a_dd,
    const int* __restrict__ dst_rev, const int* __restrict__ dst_ind,
    const int* __restrict__ dst_dd,
    bf16* __restrict__ Wh_all, float* __restrict__ el_all,
    float* __restrict__ er_all, int* __restrict__ bin_part) {
    __shared__ SharedA su;
    const int tid = threadIdx.x;

    if (blockIdx.x >= GEMMB) {
        // ---------- bin histogram branch ----------
        const int blk = blockIdx.x - GEMMB;
        for (int i = tid; i < NBIN; i += 256) su.h[i] = 0;
        __syncthreads();
        const int base = blk * CHUNK;
        const int lim = min(base + CHUNK, 3 * NEDGE);
        for (int i = base + tid; i < lim; i += 256) {
            const int t = (i >= 2 * NEDGE) ? 2 : (i >= NEDGE ? 1 : 0);
            const int e = i - t * NEDGE;
            const int d = (t == 0 ? dst_rev : (t == 1 ? dst_ind : dst_dd))[e];
            atomicAdd(&su.h[(t * N_NODE + d) >> 8], 1);
        }
        __syncthreads();
        for (int i = tid; i < NBIN; i += 256)
            bin_part[blk * NBIN + i] = su.h[i];
        return;
    }

    // ---------- GEMM branch ----------
    const int t  = blockIdx.x / GBE;
    const int mb = blockIdx.x - t * GBE;

    const float *feat, *W, *bias, *va, *vb;
    float *el_o, *er_o;
    if (t == 0)      { feat = feat_dis;  W = W_rev; bias = b_rev; va = a_rev; vb = a_ind + D; el_o = el_all;              er_o = er_all + N_NODE; }
    else if (t == 1) { feat = feat_drug; W = W_ind; bias = b_ind; va = a_ind; vb = a_rev + D; el_o = el_all + N_NODE;     er_o = er_all; }
    else             { feat = feat_dis;  W = W_dd;  bias = b_dd;  va = a_dd;  vb = a_dd + D;  el_o = el_all + 2 * N_NODE; er_o = er_all + 2 * N_NODE; }
    bf16* wh_o = Wh_all + (size_t)t * N_NODE * D;

    for (int i = tid * 4; i < D * D; i += 1024) {
        const float4 wv = *(const float4*)(W + i);
        const int k = i >> 7, n = i & (D - 1);
        su.Wt[(n + 0) * WT_LD + k] = f2bs(wv.x);
        su.Wt[(n + 1) * WT_LD + k] = f2bs(wv.y);
        su.Wt[(n + 2) * WT_LD + k] = f2bs(wv.z);
        su.Wt[(n + 3) * WT_LD + k] = f2bs(wv.w);
    }
    __syncthreads();

    const int wave = tid >> 6, lane = tid & 63;
    const int q = lane >> 4, nn = lane & 15;
    const int row0 = mb * 64 + wave * 16;
    const int arow = min(row0 + nn, N_NODE - 1);

    f32x4 acc[8];
#pragma unroll
    for (int nt = 0; nt < 8; ++nt) acc[nt] = (f32x4){0.f, 0.f, 0.f, 0.f};

#pragma unroll
    for (int ks = 0; ks < 4; ++ks) {
        const float* ap = feat + (size_t)arow * D + ks * 32 + q * 8;
        const float4 fa = *(const float4*)ap;
        const float4 fb = *(const float4*)(ap + 4);
        bf16x8 afrag;
        afrag[0] = f2bs(fa.x); afrag[1] = f2bs(fa.y);
        afrag[2] = f2bs(fa.z); afrag[3] = f2bs(fa.w);
        afrag[4] = f2bs(fb.x); afrag[5] = f2bs(fb.y);
        afrag[6] = f2bs(fb.z); afrag[7] = f2bs(fb.w);
#pragma unroll
        for (int nt = 0; nt < 8; ++nt) {
            const bf16x8 bfrag =
                *(const bf16x8*)(&su.Wt[(nt * 16 + nn) * WT_LD + ks * 32 + q * 8]);
            acc[nt] = __builtin_amdgcn_mfma_f32_16x16x32_bf16(afrag, bfrag,
                                                              acc[nt], 0, 0, 0);
        }
    }

    float biasv[8], vav[8], vbv[8];
#pragma unroll
    for (int nt = 0; nt < 8; ++nt) {
        const int col = nt * 16 + nn;
        biasv[nt] = bias[col]; vav[nt] = va[col]; vbv[nt] = vb[col];
    }
    float pel[4] = {0.f, 0.f, 0.f, 0.f};
    float per_[4] = {0.f, 0.f, 0.f, 0.f};
    short* whs = (short*)wh_o;
#pragma unroll
    for (int nt = 0; nt < 8; ++nt) {
#pragma unroll
        for (int r = 0; r < 4; ++r) {
            const float c = acc[nt][r] + biasv[nt];
            const int grow = row0 + q * 4 + r;
            if (grow < N_NODE)
                whs[(size_t)grow * D + nt * 16 + nn] = f2bs(c);
            pel[r] = fmaf(c, vav[nt], pel[r]);
            per_[r] = fmaf(c, vbv[nt], per_[r]);
        }
    }
#pragma unroll
    for (int r = 0; r < 4; ++r) {
#pragma unroll
        for (int mask = 1; mask < 16; mask <<= 1) {
            pel[r]  += __shfl_xor(pel[r],  mask, 64);
            per_[r] += __shfl_xor(per_[r], mask, 64);
        }
        const int grow = row0 + q * 4 + r;
        if (nn == 0 && grow < N_NODE) {
            el_o[grow] = pel[r];
            er_o[grow] = per_[r];
        }
    }
}

// ================================================================ K_B binscat
// Each block re-derives (from the partial-hist table, L2-hot ~207KB): the bin
// totals, their exclusive scan (bin_base), and its own deterministic run
// offset  bin_base[b] + sum_{j<blk} partial[j][b]  — no global atomics at
// all. Streams its 4096 edges into per-bin runs via LDS cursors. Payload
// u32 = (row16 << 16) | gsrc16. Block 0 publishes bin_base + row_ptr[NROW].
__global__ __launch_bounds__(256) void binscat(
    const int* __restrict__ src_rev, const int* __restrict__ dst_rev,
    const int* __restrict__ src_ind, const int* __restrict__ dst_ind,
    const int* __restrict__ src_dd,  const int* __restrict__ dst_dd,
    const int* __restrict__ bin_part, int* __restrict__ bin_base_g,
    int* __restrict__ row_ptr, unsigned* __restrict__ bin_buf) {
    __shared__ int runc[NBIN];
    __shared__ int wsum[4];
    const int blk = blockIdx.x;
    const int tid = threadIdx.x;
    const int lane = tid & 63, wave = tid >> 6;

    int tot = 0, pre = 0;
    if (tid < NBIN) {
        for (int j = 0; j < NB3; ++j) {
            const int c = bin_part[j * NBIN + tid];
            tot += c;
            pre += (j < blk) ? c : 0;
        }
    }
    // exclusive scan of tot across the 235 bins
    int v = (tid < NBIN) ? tot : 0;
    const int orig = v;
#pragma unroll
    for (int off = 1; off < 64; off <<= 1) {
        int t = __shfl_up(v, off, 64);
        if (lane >= off) v += t;
    }
    if (lane == 63) wsum[wave] = v;
    __syncthreads();
    if (tid == 0) {
        int a = 0;
#pragma unroll
        for (int w = 0; w < 4; ++w) { int t = wsum[w]; wsum[w] = a; a += t; }
    }
    __syncthreads();
    const int excl = wsum[wave] + v - orig;
    if (tid < NBIN) runc[tid] = excl + pre;
    if (blk == 0) {
        if (tid < NBIN) bin_base_g[tid] = excl;
        if (tid == 0) { bin_base_g[NBIN] = 3 * NEDGE; row_ptr[NROW] = 3 * NEDGE; }
    }
    __syncthreads();

    const int base = blk * CHUNK;
    const int lim = min(base + CHUNK, 3 * NEDGE);
    for (int i = base + tid; i < lim; i += 256) {
        const int t = (i >= 2 * NEDGE) ? 2 : (i >= NEDGE ? 1 : 0);
        const int e = i - t * NEDGE;
        const int sl = (t == 0 ? src_rev : (t == 1 ? src_ind : src_dd))[e];
        const int dl = (t == 0 ? dst_rev : (t == 1 ? dst_ind : dst_dd))[e];
        const int row = t * N_NODE + dl;
        const int slot = atomicAdd(&runc[row >> 8], 1);
        bin_buf[slot] = ((unsigned)row << 16) | (unsigned)(t * N_NODE + sl);
    }
}

// ================================================================ K_C binsort
// One block per bin; 256-row LDS count+scan -> row_ptr (coalesced) and final
// 2B edge_src16 into the bin's private contiguous region (single XCD).
__global__ __launch_bounds__(256) void binsort(
    const int* __restrict__ bin_base, const unsigned* __restrict__ bin_buf,
    int* __restrict__ row_ptr, unsigned short* __restrict__ edge_src16) {
    __shared__ int rowcnt[256];
    __shared__ int rankc[256];
    __shared__ int wsum[4];
    const int b = blockIdx.x;
    const int tid = threadIdx.x;
    const int beg = bin_base[b], end = bin_base[b + 1];
    rowcnt[tid] = 0;
    __syncthreads();
    for (int i = beg + tid; i < end; i += 256)
        atomicAdd(&rowcnt[(bin_buf[i] >> 16) & 255], 1);
    __syncthreads();
    const int lane = tid & 63, wave = tid >> 6;
    int v = rowcnt[tid];
    const int orig = v;
#pragma unroll
    for (int off = 1; off < 64; off <<= 1) {
        int t = __shfl_up(v, off, 64);
        if (lane >= off) v += t;
    }
    if (lane == 63) wsum[wave] = v;
    __syncthreads();
    if (tid == 0) {
        int a = 0;
#pragma unroll
        for (int w = 0; w < 4; ++w) { int t = wsum[w]; wsum[w] = a; a += t; }
    }
    __syncthreads();
    const int excl = wsum[wave] + v - orig;
    const int row = b * 256 + tid;
    if (row < NROW) row_ptr[row] = beg + excl;
    rankc[tid] = beg + excl;
    __syncthreads();
    for (int i = beg + tid; i < end; i += 256) {
        const unsigned u = bin_buf[i];
        const int slot = atomicAdd(&rankc[(u >> 16) & 255], 1);
        edge_src16[slot] = (unsigned short)(u & 0xFFFFu);
    }
}

// ================================================================ K_D gather
// 4 edges per memory instruction: lanes split into 4 groups of 16
// (sub = lane>>4, fl = lane&15). Each group reads a different edge's Wh row
// as dwordx4 (16 lanes x 16B = 256B row; 1KB per wave instruction). Per-edge
// meta broadcast is ONE per-lane-indexed __shfl (ds_bpermute) per 4 edges.
// Lanes >= m hold msrc=0 / mpe=0, so tail groups read row 0 with c=0 (safe,
// in-bounds, contributes nothing); t+sub <= 63 always (t <= 60, sub <= 3).
__device__ __forceinline__ void process_chunk(
    int msrc, float mpe, int m, float inv, int sub, int fl,
    const bf16* __restrict__ Wh_all, float* __restrict__ acc) {
#pragma unroll 2
    for (int t = 0; t < m; t += 4) {
        const int   s = __shfl(msrc, t + sub, 64);
        const float c = __shfl(mpe,  t + sub, 64) * inv;
        const uint4 u = ((const uint4*)(Wh_all + (size_t)s * D))[fl];
        acc[0] = fmaf(c, __uint_as_float(u.x << 16),          acc[0]);
        acc[1] = fmaf(c, __uint_as_float(u.x & 0xFFFF0000u),  acc[1]);
        acc[2] = fmaf(c, __uint_as_float(u.y << 16),          acc[2]);
        acc[3] = fmaf(c, __uint_as_float(u.y & 0xFFFF0000u),  acc[3]);
        acc[4] = fmaf(c, __uint_as_float(u.z << 16),          acc[4]);
        acc[5] = fmaf(c, __uint_as_float(u.z & 0xFFFF0000u),  acc[5]);
        acc[6] = fmaf(c, __uint_as_float(u.w << 16),          acc[6]);
        acc[7] = fmaf(c, __uint_as_float(u.w & 0xFFFF0000u),  acc[7]);
    }
}

// pass 1 loads chunk-0 edge meta into registers (avg degree ~15 < 64, so for
// nearly every row pass 2 reuses them — no reload/re-exp); deterministic
// wave-reduced softmax denominator.
__device__ __forceinline__ void do_range(
    const unsigned short* __restrict__ edge_src16,
    const float* __restrict__ el_all, float er_r,
    const bf16* __restrict__ Wh_all,
    int beg, int end, int lane, int sub, int fl, float* __restrict__ acc) {
    if (end <= beg) return;
    const int deg = end - beg;
    const int m0 = min(deg, 64);

    int msrc0 = 0; float mpe0 = 0.f;
    if (lane < m0) {
        msrc0 = edge_src16[beg + lane];
        float v = el_all[msrc0] + er_r;
        v = v > 0.f ? v : 0.01f * v;
        mpe0 = __expf(v);
    }
    float ssum = mpe0;
    for (int base = beg + 64; base < end; base += 64) {
        const int m = min(end - base, 64);
        if (lane < m) {
            const int sr = edge_src16[base + lane];
            float v = el_all[sr] + er_r;
            v = v > 0.f ? v : 0.01f * v;
            ssum += __expf(v);
        }
    }
#pragma unroll
    for (int off = 32; off > 0; off >>= 1) ssum += __shfl_down(ssum, off, 64);
    const float inv = 1.0f / __shfl(ssum, 0, 64);

    process_chunk(msrc0, mpe0, m0, inv, sub, fl, Wh_all, acc);
    for (int base = beg + 64; base < end; base += 64) {
        const int m = min(end - base, 64);
        int msrc = 0; float mpe = 0.f;
        if (lane < m) {
            msrc = edge_src16[base + lane];
            float v = el_all[msrc] + er_r;
            v = v > 0.f ? v : 0.01f * v;
            mpe = __expf(v);
        }
        process_chunk(msrc, mpe, m, inv, sub, fl, Wh_all, acc);
    }
}

// One wave per OUTPUT row w in [0,40000): w<20000 -> h_drug (CSR row w, rev);
// w>=20000 -> h_disease (CSR rows w [ind] and w+20000 [dd]). Accumulators:
// lane holds features 8*fl..8*fl+7, replicated across the 4 sub-groups;
// cross-group xor-reduce once per row, then coalesced float4 store (sub==0).
__global__ __launch_bounds__(256) void gather_all(
    const int* __restrict__ row_ptr, const unsigned short* __restrict__ edge_src16,
    const float* __restrict__ el_all, const float* __restrict__ er_all,
    const bf16* __restrict__ Wh_all, float* __restrict__ out) {
    const int w = blockIdx.x * (blockDim.x >> 6) + (threadIdx.x >> 6);
    const int lane = threadIdx.x & 63;
    if (w >= 2 * N_NODE) return;
    const int sub = lane >> 4, fl = lane & 15;

    float acc[8];
#pragma unroll
    for (int j = 0; j < 8; ++j) acc[j] = 0.f;

    do_range(edge_src16, el_all, er_all[w], Wh_all,
             row_ptr[w], row_ptr[w + 1], lane, sub, fl, acc);
    if (w >= N_NODE) {
        const int r = w + N_NODE;
        do_range(edge_src16, el_all, er_all[r], Wh_all,
                 row_ptr[r], row_ptr[r + 1], lane, sub, fl, acc);
    }

#pragma unroll
    for (int j = 0; j < 8; ++j) {
        acc[j] += __shfl_xor(acc[j], 16, 64);
        acc[j] += __shfl_xor(acc[j], 32, 64);
    }
    if (sub == 0) {
        float4* orow = (float4*)(out + (size_t)w * D);
        orow[2 * fl]     = make_float4(acc[0], acc[1], acc[2], acc[3]);
        orow[2 * fl + 1] = make_float4(acc[4], acc[5], acc[6], acc[7]);
    }
}

extern "C" void kernel_launch(void* const* d_in, const int* in_sizes, int n_in,
                              void* d_out, int out_size, void* d_ws, size_t ws_size,
                              hipStream_t stream) {
    const float* feat_drug    = (const float*)d_in[0];
    const float* feat_disease = (const float*)d_in[1];
    const float* W_ind = (const float*)d_in[2];
    const float* b_ind = (const float*)d_in[3];
    const float* a_ind = (const float*)d_in[4];
    const float* W_rev = (const float*)d_in[5];
    const float* b_rev = (const float*)d_in[6];
    const float* a_rev = (const float*)d_in[7];
    const float* W_dd  = (const float*)d_in[8];
    const float* b_dd  = (const float*)d_in[9];
    const float* a_dd  = (const float*)d_in[10];
    const int* src_ind = (const int*)d_in[11];
    const int* dst_ind = (const int*)d_in[12];
    const int* src_rev = (const int*)d_in[13];
    const int* dst_rev = (const int*)d_in[14];
    const int* src_dd  = (const int*)d_in[15];
    const int* dst_dd  = (const int*)d_in[16];
    float* out = (float*)d_out;
    (void)in_sizes; (void)n_in; (void)out_size; (void)ws_size;

    // ---- workspace: ~21.7 MB ----
    char* w = (char*)d_ws;
    bf16*  Wh_all   = (bf16*)w;                        // 15,360,000 B [rev|ind|dd]
    float* el_all   = (float*)(w + 15360000);          // 240,000 B
    float* er_all   = (float*)(w + 15600000);          // 240,000 B
    int*   row_ptr  = (int*)(w + 15840000);            // 240,004 -> pad 240,032
    int*   bin_base = (int*)(w + 16080032);            // 1,024 B (236 entries)
    int*   bin_part = (int*)(w + 16081056);            // 220*235*4 = 206,800 -> pad 206,816
    unsigned* bin_buf = (unsigned*)(w + 16287872);     // 3,600,000 B
    unsigned short* edge_src16 = (unsigned short*)(w + 19887872); // 1,800,000 B

    const int gb = (2 * N_NODE + 3) / 4;               // gather: 4 waves/block

    // K_A: 3 GEMMs + projections, overlapped with the bin histogram
    gemm_and_count<<<GEMMB + NB3, 256, 0, stream>>>(
        feat_drug, feat_disease, W_ind, b_ind, a_ind,
        W_rev, b_rev, a_rev, W_dd, b_dd, a_dd,
        dst_rev, dst_ind, dst_dd, Wh_all, el_all, er_all, bin_part);

    // K_B: deterministic binned scatter (scan derived in-kernel, no atomics)
    binscat<<<NB3, 256, 0, stream>>>(src_rev, dst_rev, src_ind, dst_ind,
                                     src_dd, dst_dd, bin_part, bin_base,
                                     row_ptr, bin_buf);

    // K_C: per-bin row sort -> row_ptr + final edge_src16
    binsort<<<NBIN, 256, 0, stream>>>(bin_base, bin_buf, row_ptr, edge_src16);

    // K_D: one gather, 40000 output rows; disease rows merge ind+dd in-register
    gather_all<<<gb, 256, 0, stream>>>(row_ptr, edge_src16, el_all, er_all,
                                       Wh_all, out);
}